// Round 11
// baseline (51.113 us; speedup 1.0000x reference)
//
#include <hip/hip_runtime.h>
#include <cstdint>
#include <cstddef>

// Problem constants
#define B_ 256
#define D_ 512
#define P_ 128
#define E_ 128

typedef unsigned short u16;
typedef unsigned int   u32;
typedef __bf16  bf16x8_t __attribute__((ext_vector_type(8)));
typedef float   f32x4_t  __attribute__((ext_vector_type(4)));
typedef u16     u16x4_t  __attribute__((ext_vector_type(4)));
typedef u16     u16x8_t  __attribute__((ext_vector_type(8)));

__device__ __forceinline__ u16 f2bf(float f) {
  union { float f; unsigned int u; } c; c.f = f;
  unsigned int u = c.u;
  unsigned int r = (u + 0x7FFFu + ((u >> 16) & 1u)) >> 16;
  return (u16)r;
}
__device__ __forceinline__ float bf2f(u16 v) {
  union { unsigned int u; float f; } c; c.u = (unsigned int)v << 16;
  return c.f;
}

// ---------------------------------------------------------------------------
// Pass 1: PREP — no LDS, no transpose, fully coalesced both sides.
// Block layouts (chunk = 8 consecutive d as one 16B unit):
//   xB[b][dc][p][8]: elem ((b*64+dc)*128+p)*8
//   wB[p][dc][e][8]: elem ((p*64+dc)*128+e)*8
// Lane = p (or e): read x[o][dc*8+j][lane] -> 256B coalesced/wave;
// write 16B chunk at lane-consecutive addresses -> 1KB coalesced/wave.
// bid<1024: x (o=b); else W (o=p). Each WG: one o, 16 dc.
// ---------------------------------------------------------------------------
__global__ __launch_bounds__(256) void prep_kernel(
    const float* __restrict__ x, const float* __restrict__ W,
    u16* __restrict__ xB, u16* __restrict__ wB) {
  const int bid  = blockIdx.x;
  const bool isX = (bid < 1024);
  const int idx  = isX ? bid : (bid - 1024);
  const int o    = idx >> 2;
  const int dc0  = (idx & 3) * 16;

  const float* src = (isX ? x : W) + (size_t)o * (D_ * 128);
  u16* dst = (isX ? xB : wB) + (size_t)o * (64 * 128 * 8);

  const int t   = threadIdx.x;
  const int c   = t & 127;        // p or e
  const int dcL = t >> 7;         // 0..1

  #pragma unroll
  for (int it = 0; it < 8; ++it) {
    const int dc = dc0 + dcL + 2 * it;
    float v[8];
    #pragma unroll
    for (int j = 0; j < 8; ++j)
      v[j] = src[(size_t)(dc * 8 + j) * 128 + c];
    u16x8_t pk;
    #pragma unroll
    for (int j = 0; j < 8; ++j) pk[j] = f2bf(v[j]);
    *reinterpret_cast<u16x8_t*>(dst + ((size_t)dc * 128 + c) * 8) = pk;
  }
}

// ---------------------------------------------------------------------------
// Pass 2: per-p bf16 TN GEMM, 128(b) x 128(e) x BK=64, 8 waves (2b x 4e),
// TRIPLE-buffered LDS (96KB), depth-3 counted-vmcnt pipeline (r9/r10
// verified schedule, unchanged). Only STAGE_AB addressing changed to the
// block layouts. Grid = 256 WGs = 1 WG/CU, XCD-swizzled p (16 p / XCD ->
// the 4-p-per-64B-line sharing of xB resolves in that XCD's L2).
// Epilogue: coalesced bf16 store to ws2[p][b][e] (+bias).
// ---------------------------------------------------------------------------

// swizzled elem index of 16B chunk g (0..7) in row `row` of a [row][64]-u16 tile
#define SWZ_ELEM(row, g) (((row) << 6) + ((((g) ^ ((row) & 7))) << 3))

__global__ __launch_bounds__(512, 2) void gemm_kernel(
    const u16* __restrict__ xB, const u16* __restrict__ wB,
    const float* __restrict__ bias, u16* __restrict__ ws2) {
  __shared__ __attribute__((aligned(16))) u16 As[3][128 * 64];
  __shared__ __attribute__((aligned(16))) u16 Bs[3][128 * 64];

  const int wg  = blockIdx.x;          // 0..255
  const int xcd = wg & 7;
  const int i   = wg >> 3;             // 0..31
  const int p   = xcd * 16 + (i & 15);
  const int b0  = (i >> 4) * 128;      // 0 or 128

  const int t    = threadIdx.x;
  const int lane = t & 63;
  const int wv   = t >> 6;             // wave 0..7
  const int wr   = wv >> 2;            // b half (0,1)
  const int wc   = wv & 3;             // e quarter (0..3)

  // staging: thread t stages 16B chunks t and t+512 of each 128x64 tile.
  // LDS dest linear; global source chunk-index pre-XOR-swizzled (rule #21).
  const int r1 = t >> 3;                           // row 0..63
  const int gs = (t & 7) ^ (r1 & 7);               // swizzled d-chunk

  const int fr = lane & 15;
  const int fq = lane >> 4;

  f32x4_t acc[4][2] = {};

#define GLOAD(gp, lp) __builtin_amdgcn_global_load_lds( \
    (const __attribute__((address_space(1))) void*)(gp), \
    (__attribute__((address_space(3))) void*)(lp), 16, 0, 0)

  // chunk elem addresses in block layouts:
  //   A (b-row, dc): ((b*64+dc)*128 + p)*8   B (e-row, dc): ((p*64+dc)*128 + e)*8
#define STAGE_AB(buf, dc0) do { \
    GLOAD(xB + (((size_t)(b0 + r1) * 64 + (dc0) + gs) * 128 + p) * 8,        &As[buf][wv * 512]); \
    GLOAD(xB + (((size_t)(b0 + r1 + 64) * 64 + (dc0) + gs) * 128 + p) * 8,   &As[buf][4096 + wv * 512]); \
    GLOAD(wB + (((size_t)p * 64 + (dc0) + gs) * 128 + r1) * 8,               &Bs[buf][wv * 512]); \
    GLOAD(wB + (((size_t)p * 64 + (dc0) + gs) * 128 + r1 + 64) * 8,          &Bs[buf][4096 + wv * 512]); \
  } while (0)

#define MFMA(a, b, c) __builtin_amdgcn_mfma_f32_16x16x32_bf16((a), (b), (c), 0, 0, 0)

#define K_ITER(KT, BUF, PREFETCH, VMSTR, LAST) do { \
    bf16x8_t af[4][2], bfr[2][2]; \
    _Pragma("unroll") \
    for (int ii = 0; ii < 4; ++ii) { \
      const int rowa = wr * 64 + ii * 16 + fr; \
      af[ii][0] = *reinterpret_cast<const bf16x8_t*>(&As[BUF][SWZ_ELEM(rowa, fq)]); \
      af[ii][1] = *reinterpret_cast<const bf16x8_t*>(&As[BUF][SWZ_ELEM(rowa, 4 + fq)]); \
    } \
    _Pragma("unroll") \
    for (int jj = 0; jj < 2; ++jj) { \
      const int rowb = wc * 32 + jj * 16 + fr; \
      bfr[jj][0] = *reinterpret_cast<const bf16x8_t*>(&Bs[BUF][SWZ_ELEM(rowb, fq)]); \
      bfr[jj][1] = *reinterpret_cast<const bf16x8_t*>(&Bs[BUF][SWZ_ELEM(rowb, 4 + fq)]); \
    } \
    asm volatile("s_waitcnt lgkmcnt(0)" ::: "memory"); \
    __builtin_amdgcn_sched_barrier(0); \
    __builtin_amdgcn_s_barrier(); \
    if (PREFETCH) STAGE_AB(BUF, ((KT) + 3) * 8); \
    _Pragma("unroll") \
    for (int kh = 0; kh < 2; ++kh) \
      _Pragma("unroll") \
      for (int ii = 0; ii < 4; ++ii) \
        _Pragma("unroll") \
        for (int jj = 0; jj < 2; ++jj) \
          acc[ii][jj] = MFMA(af[ii][kh], bfr[jj][kh], acc[ii][jj]); \
    if (!(LAST)) { \
      asm volatile("s_waitcnt " VMSTR ::: "memory"); \
      __builtin_amdgcn_sched_barrier(0); \
      __builtin_amdgcn_s_barrier(); \
    } \
  } while (0)

  // ---- prologue: tiles 0,1,2 in flight; wait tile 0; barrier ----
  STAGE_AB(0, 0);
  STAGE_AB(1, 8);
  STAGE_AB(2, 16);
  asm volatile("s_waitcnt vmcnt(8)" ::: "memory");   // tile 0's 4 loads landed
  __builtin_amdgcn_sched_barrier(0);
  __builtin_amdgcn_s_barrier();

  K_ITER(0, 0, 1, "vmcnt(8)", 0);   // stages tile 3 -> buf0
  K_ITER(1, 1, 1, "vmcnt(8)", 0);   // tile 4 -> buf1
  K_ITER(2, 2, 1, "vmcnt(8)", 0);   // tile 5 -> buf2
  K_ITER(3, 0, 1, "vmcnt(8)", 0);   // tile 6 -> buf0
  K_ITER(4, 1, 1, "vmcnt(8)", 0);   // tile 7 -> buf1
  K_ITER(5, 2, 0, "vmcnt(4)", 0);   // wait tile 6
  K_ITER(6, 0, 0, "vmcnt(0)", 0);   // wait tile 7
  K_ITER(7, 1, 0, "vmcnt(0)", 1);

#undef K_ITER
#undef MFMA
#undef STAGE_AB
#undef GLOAD

  // ---- epilogue: coalesced bf16 store to ws2[p][b][e] (+bias) ----
  const int q4 = fq * 4;
  #pragma unroll
  for (int jj = 0; jj < 2; ++jj) {
    const int e  = wc * 32 + jj * 16 + fr;
    const float bv = bias[p * E_ + e];
    #pragma unroll
    for (int ii = 0; ii < 4; ++ii) {
      const int r0 = b0 + wr * 64 + ii * 16 + q4;
      #pragma unroll
      for (int rg = 0; rg < 4; ++rg) {
        ws2[((size_t)p * B_ + (r0 + rg)) * E_ + e] = f2bf(acc[ii][jj][rg] + bv);
      }
    }
  }
}

// ---------------------------------------------------------------------------
// Pass 3: ws2[p][b][e] bf16 -> out[b][e][p] f32; padded-LDS 64x64 transpose,
// coalesced read (e-contiguous bf16) and write (p-contiguous float4).
// Grid: (b=256, pblk=2, eblk=2).
// ---------------------------------------------------------------------------
__global__ __launch_bounds__(256) void out_transpose_kernel(
    const u16* __restrict__ ws2, float* __restrict__ out) {
  __shared__ float tile[64][65];

  const int b  = blockIdx.x;
  const int p0 = blockIdx.y * 64;
  const int e0 = blockIdx.z * 64;
  const int t  = threadIdx.x;

  const u16* s = ws2 + ((size_t)p0 * B_ + b) * E_ + e0;   // p-row stride B_*E_

  {
    const int lr = t >> 4;          // p-local row 0..15
    const int lc = (t & 15) * 4;    // e-local col
    #pragma unroll
    for (int it = 0; it < 4; ++it) {
      const int r = lr + it * 16;
      const u16x4_t v = *reinterpret_cast<const u16x4_t*>(s + (size_t)r * (B_ * E_) + lc);
      tile[r][lc + 0] = bf2f(v[0]); tile[r][lc + 1] = bf2f(v[1]);
      tile[r][lc + 2] = bf2f(v[2]); tile[r][lc + 3] = bf2f(v[3]);
    }
  }
  __syncthreads();

  {
    const int c  = t >> 4;          // e-local col base
    const int wd = (t & 15) * 4;    // p-local row chunk
    #pragma unroll
    for (int it = 0; it < 4; ++it) {
      const int cc = c + it * 16;
      float4 v;
      v.x = tile[wd + 0][cc]; v.y = tile[wd + 1][cc];
      v.z = tile[wd + 2][cc]; v.w = tile[wd + 3][cc];
      *reinterpret_cast<float4*>(out + ((size_t)b * E_ + e0 + cc) * P_ + p0 + wd) = v;
    }
  }
}

// ---------------------------------------------------------------------------
// Fallback (only if workspace is too small): naive but correct.
// ---------------------------------------------------------------------------
__global__ __launch_bounds__(256) void naive_kernel(
    const float* __restrict__ x, const float* __restrict__ W,
    const float* __restrict__ bias, float* __restrict__ out) {
  const size_t idx = (size_t)blockIdx.x * 256 + threadIdx.x;
  const int p = (int)(idx & 127);
  const int e = (int)((idx >> 7) & 127);
  const int b = (int)(idx >> 14);
  float acc = bias[p * E_ + e];
  const float* xp = x + (size_t)b * D_ * P_ + p;
  const float* wp = W + (size_t)p * D_ * E_ + e;
  for (int d = 0; d < D_; ++d) acc += xp[(size_t)d * P_] * wp[(size_t)d * E_];
  out[idx] = acc;
}

extern "C" void kernel_launch(void* const* d_in, const int* in_sizes, int n_in,
                              void* d_out, int out_size, void* d_ws, size_t ws_size,
                              hipStream_t stream) {
  (void)in_sizes; (void)n_in; (void)out_size;
  const float* x    = (const float*)d_in[0];   // [B,D,P] f32
  const float* W    = (const float*)d_in[1];   // [P,D,E] f32
  const float* bias = (const float*)d_in[2];   // [P,E]   f32
  float* out = (float*)d_out;                  // [B,E,P] f32

  const size_t xB_bytes  = (size_t)B_ * 64 * 128 * 8 * 2;   // 32 MiB
  const size_t wB_bytes  = (size_t)P_ * 64 * 128 * 8 * 2;   // 16 MiB
  const size_t ws2_bytes = (size_t)P_ * B_ * E_ * 2;        // 8 MiB

  if (ws_size < xB_bytes + wB_bytes + ws2_bytes) {
    naive_kernel<<<dim3((B_ * E_ * P_) / 256), 256, 0, stream>>>(x, W, bias, out);
    return;
  }

  u16* xB  = (u16*)d_ws;                                    // [B][64][128][8]
  u16* wB  = (u16*)((char*)d_ws + xB_bytes);                // [P][64][128][8]
  u16* ws2 = (u16*)((char*)d_ws + xB_bytes + wB_bytes);     // [P][B][E]

  // x: 1024 blocks (256 b x 4 dc-blocks); W: 512 blocks (128 p x 4)
  prep_kernel<<<dim3(1536), 256, 0, stream>>>(x, W, xB, wB);
  gemm_kernel<<<dim3(256), 512, 0, stream>>>(xB, wB, bias, ws2);
  out_transpose_kernel<<<dim3(B_, 2, 2), 256, 0, stream>>>(ws2, out);
}

// Round 12
// 43.653 us; speedup vs baseline: 1.1709x; 1.1709x over previous
//
#include <hip/hip_runtime.h>
#include <cstdint>
#include <cstddef>

// Problem constants
#define B_ 256
#define D_ 512
#define P_ 128
#define E_ 128

typedef unsigned short u16;
typedef unsigned int   u32;
typedef __bf16  bf16x8_t __attribute__((ext_vector_type(8)));
typedef float   f32x4_t  __attribute__((ext_vector_type(4)));
typedef u16     u16x4_t  __attribute__((ext_vector_type(4)));
typedef u16     u16x8_t  __attribute__((ext_vector_type(8)));
typedef u32     u32x4_t  __attribute__((ext_vector_type(4)));

__device__ __forceinline__ u16 f2bf(float f) {
  union { float f; unsigned int u; } c; c.f = f;
  unsigned int u = c.u;
  unsigned int r = (u + 0x7FFFu + ((u >> 16) & 1u)) >> 16;
  return (u16)r;
}
__device__ __forceinline__ u32 pk2bf(float a, float b) {
  return (u32)f2bf(a) | ((u32)f2bf(b) << 16);
}
__device__ __forceinline__ float bf2f(u16 v) {
  union { unsigned int u; float f; } c; c.u = (unsigned int)v << 16;
  return c.f;
}

// ---------------------------------------------------------------------------
// Pass 1: PREP — fully vectorized (float4 reads, b128 LDS ops, b128 stores).
// k-permutation trick: chunk kc holds d = 16*(kc>>1) + (kc&1) + 2j (j=0..7).
// A 64-lane float4 read covers rows (d, d+1): lanes<32 accumulate even-d,
// lanes>=32 odd-d -> after 8 reads each lane packs 4 FULL 16B chunks from
// its own registers (no cross-lane). Chunks pass through a 32KB LDS tile
// (XOR-swizzled b128, conflict-free) and exit as 256B-contiguous runs.
// The GEMM pairs A/B chunks by index, so any shared k<->d bijection is exact.
// bid<1024: x (o=b) -> xT[p][b][kc]; else W (o=p) -> Wt[p][e][kc].
// ---------------------------------------------------------------------------
__global__ __launch_bounds__(256, 4) void prep_kernel(
    const float* __restrict__ x, const float* __restrict__ W,
    u16* __restrict__ xT, u16* __restrict__ Wt) {
  __shared__ __attribute__((aligned(16))) u32 lds[128 * 16 * 4];  // 32 KB

  const int bid  = blockIdx.x;
  const bool isX = (bid < 1024);
  const int idx  = isX ? bid : (bid - 1024);
  const int o    = idx >> 2;
  const int dblk = idx & 3;                  // d-base = dblk*128
  const float* src = (isX ? x : W) + (size_t)o * (D_ * 128) + (size_t)dblk * (128 * 128);
  u16* dst = isX ? xT : Wt;
  const size_t crs = isX ? (size_t)(256 * 64) : (size_t)64;   // chunk stride per column idx
  const size_t ors = isX ? (size_t)64 : (size_t)(128 * 64);   // chunk stride per o
  const int kcG0 = dblk * 16;

  const int t    = threadIdx.x;
  const int wv   = t >> 6;
  const int lane = t & 63;
  const int c5   = lane & 31;
  const int par  = lane >> 5;

  // ---- phase A: read 16 d-rows x 128 cols per iter, pack chunks in regs ----
  #pragma unroll
  for (int i2 = 0; i2 < 2; ++i2) {
    const int dc16 = wv + 4 * i2;            // 0..7
    f32x4_t v[8];
    #pragma unroll
    for (int j = 0; j < 8; ++j)
      v[j] = *reinterpret_cast<const f32x4_t*>(
          src + (size_t)(dc16 * 16 + 2 * j + par) * 128 + c5 * 4);
    const int kcL = dc16 * 2 + par;          // 0..15
    #pragma unroll
    for (int q = 0; q < 4; ++q) {
      const int p = 4 * c5 + q;
      u32x4_t ch;
      ch[0] = pk2bf(v[0][q], v[1][q]);
      ch[1] = pk2bf(v[2][q], v[3][q]);
      ch[2] = pk2bf(v[4][q], v[5][q]);
      ch[3] = pk2bf(v[6][q], v[7][q]);
      const int unit = p * 16 + (kcL ^ (c5 & 15));
      *reinterpret_cast<u32x4_t*>(&lds[unit * 4]) = ch;
    }
  }
  __syncthreads();

  // ---- phase B: emit 256B-contiguous chunk runs per column index ----
  {
    const int kcL = t & 15;
    #pragma unroll
    for (int j = 0; j < 8; ++j) {
      const int p = (t >> 4) + 16 * j;
      const int unit = p * 16 + (kcL ^ ((p >> 2) & 15));
      const u32x4_t ch = *reinterpret_cast<const u32x4_t*>(&lds[unit * 4]);
      *reinterpret_cast<u32x4_t*>(dst + ((size_t)p * crs + (size_t)o * ors + kcG0 + kcL) * 8) = ch;
    }
  }
}

// ---------------------------------------------------------------------------
// Pass 2: per-p bf16 TN GEMM (r10 dense-row staging restored). Tile
// 128(b) x 128(e) x BK=64, 8 waves (2b x 4e), DOUBLE-buffered LDS (64KB,
// 2 WG/CU), depth-2 counted-vmcnt pipeline (r5-verified schedule).
// Grid = 256 WGs, XCD-swizzled p. Epilogue: coalesced bf16 ws2[p][b][e].
// ---------------------------------------------------------------------------

// swizzled elem index of 16B chunk g (0..7) in row `row` of a [row][64]-u16 tile
#define SWZ_ELEM(row, g) (((row) << 6) + ((((g) ^ ((row) & 7))) << 3))

__global__ __launch_bounds__(512, 2) void gemm_kernel(
    const u16* __restrict__ xT, const u16* __restrict__ Wt,
    const float* __restrict__ bias, u16* __restrict__ ws2) {
  __shared__ __attribute__((aligned(16))) u16 As[2][128 * 64];
  __shared__ __attribute__((aligned(16))) u16 Bs[2][128 * 64];

  const int wg  = blockIdx.x;          // 0..255
  const int xcd = wg & 7;
  const int i   = wg >> 3;             // 0..31
  const int p   = xcd * 16 + (i & 15);
  const int b0  = (i >> 4) * 128;      // 0 or 128

  const int t    = threadIdx.x;
  const int lane = t & 63;
  const int wv   = t >> 6;             // wave 0..7
  const int wr   = wv >> 2;            // b half (0,1)
  const int wc   = wv & 3;             // e quarter (0..3)

  const u16* Ag = xT + (size_t)p * (B_ * D_) + (size_t)b0 * D_;
  const u16* Bg = Wt + (size_t)p * (E_ * D_);

  // staging: thread t stages 16B chunks t and t+512; LDS dest linear,
  // global source chunk pre-XOR-swizzled within its 128B row group.
  const int r1 = t >> 3;                           // row 0..63
  const int sw = (((t & 7) ^ (r1 & 7)) << 3);      // swizzled elem offset

  const int fr = lane & 15;
  const int fq = lane >> 4;

  f32x4_t acc[4][2] = {};

#define GLOAD(gp, lp) __builtin_amdgcn_global_load_lds( \
    (const __attribute__((address_space(1))) void*)(gp), \
    (__attribute__((address_space(3))) void*)(lp), 16, 0, 0)

#define STAGE_AB(buf, d0) do { \
    GLOAD(Ag + (size_t)r1 * D_ + (d0) + sw,        &As[buf][wv * 512]); \
    GLOAD(Ag + (size_t)(r1 + 64) * D_ + (d0) + sw, &As[buf][4096 + wv * 512]); \
    GLOAD(Bg + (size_t)r1 * D_ + (d0) + sw,        &Bs[buf][wv * 512]); \
    GLOAD(Bg + (size_t)(r1 + 64) * D_ + (d0) + sw, &Bs[buf][4096 + wv * 512]); \
  } while (0)

#define MFMA(a, b, c) __builtin_amdgcn_mfma_f32_16x16x32_bf16((a), (b), (c), 0, 0, 0)

#define K_ITER(KT, PREFETCH, VMSTR, LAST) do { \
    bf16x8_t af[4][2], bfr[2][2]; \
    _Pragma("unroll") \
    for (int ii = 0; ii < 4; ++ii) { \
      const int rowa = wr * 64 + ii * 16 + fr; \
      af[ii][0] = *reinterpret_cast<const bf16x8_t*>(&As[(KT) & 1][SWZ_ELEM(rowa, fq)]); \
      af[ii][1] = *reinterpret_cast<const bf16x8_t*>(&As[(KT) & 1][SWZ_ELEM(rowa, 4 + fq)]); \
    } \
    _Pragma("unroll") \
    for (int jj = 0; jj < 2; ++jj) { \
      const int rowb = wc * 32 + jj * 16 + fr; \
      bfr[jj][0] = *reinterpret_cast<const bf16x8_t*>(&Bs[(KT) & 1][SWZ_ELEM(rowb, fq)]); \
      bfr[jj][1] = *reinterpret_cast<const bf16x8_t*>(&Bs[(KT) & 1][SWZ_ELEM(rowb, 4 + fq)]); \
    } \
    asm volatile("s_waitcnt lgkmcnt(0)" ::: "memory"); \
    __builtin_amdgcn_sched_barrier(0); \
    __builtin_amdgcn_s_barrier(); \
    if (PREFETCH) STAGE_AB((KT) & 1, ((KT) + 2) * 64); \
    _Pragma("unroll") \
    for (int kh = 0; kh < 2; ++kh) \
      _Pragma("unroll") \
      for (int ii = 0; ii < 4; ++ii) \
        _Pragma("unroll") \
        for (int jj = 0; jj < 2; ++jj) \
          acc[ii][jj] = MFMA(af[ii][kh], bfr[jj][kh], acc[ii][jj]); \
    if (!(LAST)) { \
      asm volatile("s_waitcnt " VMSTR ::: "memory"); \
      __builtin_amdgcn_sched_barrier(0); \
      __builtin_amdgcn_s_barrier(); \
    } \
  } while (0)

  // ---- prologue: tiles 0,1 in flight; wait tile 0; barrier ----
  STAGE_AB(0, 0);
  STAGE_AB(1, 64);
  asm volatile("s_waitcnt vmcnt(4)" ::: "memory");   // tile 0's 4 loads landed
  __builtin_amdgcn_sched_barrier(0);
  __builtin_amdgcn_s_barrier();

  K_ITER(0, 1, "vmcnt(4)", 0);
  K_ITER(1, 1, "vmcnt(4)", 0);
  K_ITER(2, 1, "vmcnt(4)", 0);
  K_ITER(3, 1, "vmcnt(4)", 0);
  K_ITER(4, 1, "vmcnt(4)", 0);
  K_ITER(5, 1, "vmcnt(4)", 0);
  K_ITER(6, 0, "vmcnt(0)", 0);
  K_ITER(7, 0, "vmcnt(0)", 1);

#undef K_ITER
#undef MFMA
#undef STAGE_AB
#undef GLOAD

  // ---- epilogue: coalesced bf16 store to ws2[p][b][e] (+bias) ----
  const int q4 = fq * 4;
  #pragma unroll
  for (int jj = 0; jj < 2; ++jj) {
    const int e  = wc * 32 + jj * 16 + fr;
    const float bv = bias[p * E_ + e];
    #pragma unroll
    for (int ii = 0; ii < 4; ++ii) {
      const int r0 = b0 + wr * 64 + ii * 16 + q4;
      #pragma unroll
      for (int rg = 0; rg < 4; ++rg) {
        ws2[((size_t)p * B_ + (r0 + rg)) * E_ + e] = f2bf(acc[ii][jj][rg] + bv);
      }
    }
  }
}

// ---------------------------------------------------------------------------
// Pass 3: ws2[p][b][e] bf16 -> out[b][e][p] f32; padded-LDS 64x64 transpose,
// coalesced read (e-contiguous bf16) and write (p-contiguous float4).
// Grid: (b=256, pblk=2, eblk=2).
// ---------------------------------------------------------------------------
__global__ __launch_bounds__(256) void out_transpose_kernel(
    const u16* __restrict__ ws2, float* __restrict__ out) {
  __shared__ float tile[64][65];

  const int b  = blockIdx.x;
  const int p0 = blockIdx.y * 64;
  const int e0 = blockIdx.z * 64;
  const int t  = threadIdx.x;

  const u16* s = ws2 + ((size_t)p0 * B_ + b) * E_ + e0;   // p-row stride B_*E_

  {
    const int lr = t >> 4;          // p-local row 0..15
    const int lc = (t & 15) * 4;    // e-local col
    #pragma unroll
    for (int it = 0; it < 4; ++it) {
      const int r = lr + it * 16;
      const u16x4_t v = *reinterpret_cast<const u16x4_t*>(s + (size_t)r * (B_ * E_) + lc);
      tile[r][lc + 0] = bf2f(v[0]); tile[r][lc + 1] = bf2f(v[1]);
      tile[r][lc + 2] = bf2f(v[2]); tile[r][lc + 3] = bf2f(v[3]);
    }
  }
  __syncthreads();

  {
    const int c  = t >> 4;          // e-local col base
    const int wd = (t & 15) * 4;    // p-local row chunk
    #pragma unroll
    for (int it = 0; it < 4; ++it) {
      const int cc = c + it * 16;
      float4 v;
      v.x = tile[wd + 0][cc]; v.y = tile[wd + 1][cc];
      v.z = tile[wd + 2][cc]; v.w = tile[wd + 3][cc];
      *reinterpret_cast<float4*>(out + ((size_t)b * E_ + e0 + cc) * P_ + p0 + wd) = v;
    }
  }
}

// ---------------------------------------------------------------------------
// Fallback (only if workspace is too small): naive but correct.
// ---------------------------------------------------------------------------
__global__ __launch_bounds__(256) void naive_kernel(
    const float* __restrict__ x, const float* __restrict__ W,
    const float* __restrict__ bias, float* __restrict__ out) {
  const size_t idx = (size_t)blockIdx.x * 256 + threadIdx.x;
  const int p = (int)(idx & 127);
  const int e = (int)((idx >> 7) & 127);
  const int b = (int)(idx >> 14);
  float acc = bias[p * E_ + e];
  const float* xp = x + (size_t)b * D_ * P_ + p;
  const float* wp = W + (size_t)p * D_ * E_ + e;
  for (int d = 0; d < D_; ++d) acc += xp[(size_t)d * P_] * wp[(size_t)d * E_];
  out[idx] = acc;
}

extern "C" void kernel_launch(void* const* d_in, const int* in_sizes, int n_in,
                              void* d_out, int out_size, void* d_ws, size_t ws_size,
                              hipStream_t stream) {
  (void)in_sizes; (void)n_in; (void)out_size;
  const float* x    = (const float*)d_in[0];   // [B,D,P] f32
  const float* W    = (const float*)d_in[1];   // [P,D,E] f32
  const float* bias = (const float*)d_in[2];   // [P,E]   f32
  float* out = (float*)d_out;                  // [B,E,P] f32

  const size_t xT_bytes  = (size_t)P_ * B_ * D_ * 2;   // 32 MiB
  const size_t Wt_bytes  = (size_t)P_ * E_ * D_ * 2;   // 16 MiB
  const size_t ws2_bytes = (size_t)P_ * B_ * E_ * 2;   // 8 MiB

  if (ws_size < xT_bytes + Wt_bytes + ws2_bytes) {
    naive_kernel<<<dim3((B_ * E_ * P_) / 256), 256, 0, stream>>>(x, W, bias, out);
    return;
  }

  u16* xT  = (u16*)d_ws;                                    // [P][B][64 kc][8]
  u16* Wt  = (u16*)((char*)d_ws + xT_bytes);                // [P][E][64 kc][8]
  u16* ws2 = (u16*)((char*)d_ws + xT_bytes + Wt_bytes);     // [P][B][E]

  // x: 1024 blocks (256 b x 4 d-blocks); W: 512 blocks (128 p x 4)
  prep_kernel<<<dim3(1536), 256, 0, stream>>>(x, W, xT, Wt);
  gemm_kernel<<<dim3(256), 512, 0, stream>>>(xT, Wt, bias, ws2);
  out_transpose_kernel<<<dim3(B_, 2, 2), 256, 0, stream>>>(ws2, out);
}

// Round 13
// 43.608 us; speedup vs baseline: 1.1721x; 1.0010x over previous
//
#include <hip/hip_runtime.h>
#include <cstdint>
#include <cstddef>

// Problem constants
#define B_ 256
#define D_ 512
#define P_ 128
#define E_ 128

typedef unsigned short u16;
typedef unsigned int   u32;
typedef __bf16  bf16x8_t __attribute__((ext_vector_type(8)));
typedef float   f32x4_t  __attribute__((ext_vector_type(4)));
typedef u16     u16x4_t  __attribute__((ext_vector_type(4)));
typedef u16     u16x8_t  __attribute__((ext_vector_type(8)));
typedef u32     u32x4_t  __attribute__((ext_vector_type(4)));

__device__ __forceinline__ u16 f2bf(float f) {
  union { float f; unsigned int u; } c; c.f = f;
  unsigned int u = c.u;
  unsigned int r = (u + 0x7FFFu + ((u >> 16) & 1u)) >> 16;
  return (u16)r;
}
__device__ __forceinline__ u32 pk2bf(float a, float b) {
  return (u32)f2bf(a) | ((u32)f2bf(b) << 16);
}
__device__ __forceinline__ float bf2f(u16 v) {
  union { unsigned int u; float f; } c; c.u = (unsigned int)v << 16;
  return c.f;
}

// ---------------------------------------------------------------------------
// Pass 1: PREP (r12-verified, at BW floor) — fully vectorized.
// k-permutation: chunk kc holds d = 16*(kc>>1) + (kc&1) + 2j (j=0..7); the
// GEMM pairs A/B chunks by index so the bijection cancels exactly.
// bid<1024: x (o=b) -> xT[p][b][kc]; else W (o=p) -> Wt[p][e][kc].
// ---------------------------------------------------------------------------
__global__ __launch_bounds__(256, 4) void prep_kernel(
    const float* __restrict__ x, const float* __restrict__ W,
    u16* __restrict__ xT, u16* __restrict__ Wt) {
  __shared__ __attribute__((aligned(16))) u32 lds[128 * 16 * 4];  // 32 KB

  const int bid  = blockIdx.x;
  const bool isX = (bid < 1024);
  const int idx  = isX ? bid : (bid - 1024);
  const int o    = idx >> 2;
  const int dblk = idx & 3;                  // d-base = dblk*128
  const float* src = (isX ? x : W) + (size_t)o * (D_ * 128) + (size_t)dblk * (128 * 128);
  u16* dst = isX ? xT : Wt;
  const size_t crs = isX ? (size_t)(256 * 64) : (size_t)64;   // chunk stride per column idx
  const size_t ors = isX ? (size_t)64 : (size_t)(128 * 64);   // chunk stride per o
  const int kcG0 = dblk * 16;

  const int t    = threadIdx.x;
  const int wv   = t >> 6;
  const int lane = t & 63;
  const int c5   = lane & 31;
  const int par  = lane >> 5;

  // ---- phase A: read 16 d-rows x 128 cols per iter, pack chunks in regs ----
  #pragma unroll
  for (int i2 = 0; i2 < 2; ++i2) {
    const int dc16 = wv + 4 * i2;            // 0..7
    f32x4_t v[8];
    #pragma unroll
    for (int j = 0; j < 8; ++j)
      v[j] = *reinterpret_cast<const f32x4_t*>(
          src + (size_t)(dc16 * 16 + 2 * j + par) * 128 + c5 * 4);
    const int kcL = dc16 * 2 + par;          // 0..15
    #pragma unroll
    for (int q = 0; q < 4; ++q) {
      const int p = 4 * c5 + q;
      u32x4_t ch;
      ch[0] = pk2bf(v[0][q], v[1][q]);
      ch[1] = pk2bf(v[2][q], v[3][q]);
      ch[2] = pk2bf(v[4][q], v[5][q]);
      ch[3] = pk2bf(v[6][q], v[7][q]);
      const int unit = p * 16 + (kcL ^ (c5 & 15));
      *reinterpret_cast<u32x4_t*>(&lds[unit * 4]) = ch;
    }
  }
  __syncthreads();

  // ---- phase B: emit 256B-contiguous chunk runs per column index ----
  {
    const int kcL = t & 15;
    #pragma unroll
    for (int j = 0; j < 8; ++j) {
      const int p = (t >> 4) + 16 * j;
      const int unit = p * 16 + (kcL ^ ((p >> 2) & 15));
      const u32x4_t ch = *reinterpret_cast<const u32x4_t*>(&lds[unit * 4]);
      *reinterpret_cast<u32x4_t*>(dst + ((size_t)p * crs + (size_t)o * ors + kcG0 + kcL) * 8) = ch;
    }
  }
}

// ---------------------------------------------------------------------------
// Pass 2: per-p bf16 TN GEMM, 128(b) x 128(e) x BK=64, 8 waves (2b x 4e),
// TRIPLE-buffered LDS (96KB, 1 WG/CU), depth-3 counted-vmcnt pipeline
// (r10-verified schedule) on r12's verified dense-row k-permuted layout.
// Grid = 256 WGs, XCD-swizzled p. Epilogue: coalesced bf16 ws2[p][b][e].
// ---------------------------------------------------------------------------

// swizzled elem index of 16B chunk g (0..7) in row `row` of a [row][64]-u16 tile
#define SWZ_ELEM(row, g) (((row) << 6) + ((((g) ^ ((row) & 7))) << 3))

__global__ __launch_bounds__(512, 2) void gemm_kernel(
    const u16* __restrict__ xT, const u16* __restrict__ Wt,
    const float* __restrict__ bias, u16* __restrict__ ws2) {
  __shared__ __attribute__((aligned(16))) u16 As[3][128 * 64];
  __shared__ __attribute__((aligned(16))) u16 Bs[3][128 * 64];

  const int wg  = blockIdx.x;          // 0..255
  const int xcd = wg & 7;
  const int i   = wg >> 3;             // 0..31
  const int p   = xcd * 16 + (i & 15);
  const int b0  = (i >> 4) * 128;      // 0 or 128

  const int t    = threadIdx.x;
  const int lane = t & 63;
  const int wv   = t >> 6;             // wave 0..7
  const int wr   = wv >> 2;            // b half (0,1)
  const int wc   = wv & 3;             // e quarter (0..3)

  const u16* Ag = xT + (size_t)p * (B_ * D_) + (size_t)b0 * D_;
  const u16* Bg = Wt + (size_t)p * (E_ * D_);

  // staging: thread t stages 16B chunks t and t+512; LDS dest linear,
  // global source chunk pre-XOR-swizzled within its 128B row group.
  const int r1 = t >> 3;                           // row 0..63
  const int sw = (((t & 7) ^ (r1 & 7)) << 3);      // swizzled elem offset

  const int fr = lane & 15;
  const int fq = lane >> 4;

  f32x4_t acc[4][2] = {};

#define GLOAD(gp, lp) __builtin_amdgcn_global_load_lds( \
    (const __attribute__((address_space(1))) void*)(gp), \
    (__attribute__((address_space(3))) void*)(lp), 16, 0, 0)

#define STAGE_AB(buf, d0) do { \
    GLOAD(Ag + (size_t)r1 * D_ + (d0) + sw,        &As[buf][wv * 512]); \
    GLOAD(Ag + (size_t)(r1 + 64) * D_ + (d0) + sw, &As[buf][4096 + wv * 512]); \
    GLOAD(Bg + (size_t)r1 * D_ + (d0) + sw,        &Bs[buf][wv * 512]); \
    GLOAD(Bg + (size_t)(r1 + 64) * D_ + (d0) + sw, &Bs[buf][4096 + wv * 512]); \
  } while (0)

#define MFMA(a, b, c) __builtin_amdgcn_mfma_f32_16x16x32_bf16((a), (b), (c), 0, 0, 0)

#define K_ITER(KT, BUF, PREFETCH, VMSTR, LAST) do { \
    bf16x8_t af[4][2], bfr[2][2]; \
    _Pragma("unroll") \
    for (int ii = 0; ii < 4; ++ii) { \
      const int rowa = wr * 64 + ii * 16 + fr; \
      af[ii][0] = *reinterpret_cast<const bf16x8_t*>(&As[BUF][SWZ_ELEM(rowa, fq)]); \
      af[ii][1] = *reinterpret_cast<const bf16x8_t*>(&As[BUF][SWZ_ELEM(rowa, 4 + fq)]); \
    } \
    _Pragma("unroll") \
    for (int jj = 0; jj < 2; ++jj) { \
      const int rowb = wc * 32 + jj * 16 + fr; \
      bfr[jj][0] = *reinterpret_cast<const bf16x8_t*>(&Bs[BUF][SWZ_ELEM(rowb, fq)]); \
      bfr[jj][1] = *reinterpret_cast<const bf16x8_t*>(&Bs[BUF][SWZ_ELEM(rowb, 4 + fq)]); \
    } \
    asm volatile("s_waitcnt lgkmcnt(0)" ::: "memory"); \
    __builtin_amdgcn_sched_barrier(0); \
    __builtin_amdgcn_s_barrier(); \
    if (PREFETCH) STAGE_AB(BUF, ((KT) + 3) * 64); \
    _Pragma("unroll") \
    for (int kh = 0; kh < 2; ++kh) \
      _Pragma("unroll") \
      for (int ii = 0; ii < 4; ++ii) \
        _Pragma("unroll") \
        for (int jj = 0; jj < 2; ++jj) \
          acc[ii][jj] = MFMA(af[ii][kh], bfr[jj][kh], acc[ii][jj]); \
    if (!(LAST)) { \
      asm volatile("s_waitcnt " VMSTR ::: "memory"); \
      __builtin_amdgcn_sched_barrier(0); \
      __builtin_amdgcn_s_barrier(); \
    } \
  } while (0)

  // ---- prologue: tiles 0,1,2 in flight; wait tile 0; barrier ----
  STAGE_AB(0, 0);
  STAGE_AB(1, 64);
  STAGE_AB(2, 128);
  asm volatile("s_waitcnt vmcnt(8)" ::: "memory");   // tile 0's 4 loads landed
  __builtin_amdgcn_sched_barrier(0);
  __builtin_amdgcn_s_barrier();

  K_ITER(0, 0, 1, "vmcnt(8)", 0);   // stages tile 3 -> buf0
  K_ITER(1, 1, 1, "vmcnt(8)", 0);   // tile 4 -> buf1
  K_ITER(2, 2, 1, "vmcnt(8)", 0);   // tile 5 -> buf2
  K_ITER(3, 0, 1, "vmcnt(8)", 0);   // tile 6 -> buf0
  K_ITER(4, 1, 1, "vmcnt(8)", 0);   // tile 7 -> buf1
  K_ITER(5, 2, 0, "vmcnt(4)", 0);   // wait tile 6
  K_ITER(6, 0, 0, "vmcnt(0)", 0);   // wait tile 7
  K_ITER(7, 1, 0, "vmcnt(0)", 1);

#undef K_ITER
#undef MFMA
#undef STAGE_AB
#undef GLOAD

  // ---- epilogue: coalesced bf16 store to ws2[p][b][e] (+bias) ----
  const int q4 = fq * 4;
  #pragma unroll
  for (int jj = 0; jj < 2; ++jj) {
    const int e  = wc * 32 + jj * 16 + fr;
    const float bv = bias[p * E_ + e];
    #pragma unroll
    for (int ii = 0; ii < 4; ++ii) {
      const int r0 = b0 + wr * 64 + ii * 16 + q4;
      #pragma unroll
      for (int rg = 0; rg < 4; ++rg) {
        ws2[((size_t)p * B_ + (r0 + rg)) * E_ + e] = f2bf(acc[ii][jj][rg] + bv);
      }
    }
  }
}

// ---------------------------------------------------------------------------
// Pass 3: ws2[p][b][e] bf16 -> out[b][e][p] f32; padded-LDS 64x64 transpose,
// coalesced read (e-contiguous bf16) and write (p-contiguous float4).
// Grid: (b=256, pblk=2, eblk=2).
// ---------------------------------------------------------------------------
__global__ __launch_bounds__(256) void out_transpose_kernel(
    const u16* __restrict__ ws2, float* __restrict__ out) {
  __shared__ float tile[64][65];

  const int b  = blockIdx.x;
  const int p0 = blockIdx.y * 64;
  const int e0 = blockIdx.z * 64;
  const int t  = threadIdx.x;

  const u16* s = ws2 + ((size_t)p0 * B_ + b) * E_ + e0;   // p-row stride B_*E_

  {
    const int lr = t >> 4;          // p-local row 0..15
    const int lc = (t & 15) * 4;    // e-local col
    #pragma unroll
    for (int it = 0; it < 4; ++it) {
      const int r = lr + it * 16;
      const u16x4_t v = *reinterpret_cast<const u16x4_t*>(s + (size_t)r * (B_ * E_) + lc);
      tile[r][lc + 0] = bf2f(v[0]); tile[r][lc + 1] = bf2f(v[1]);
      tile[r][lc + 2] = bf2f(v[2]); tile[r][lc + 3] = bf2f(v[3]);
    }
  }
  __syncthreads();

  {
    const int c  = t >> 4;          // e-local col base
    const int wd = (t & 15) * 4;    // p-local row chunk
    #pragma unroll
    for (int it = 0; it < 4; ++it) {
      const int cc = c + it * 16;
      float4 v;
      v.x = tile[wd + 0][cc]; v.y = tile[wd + 1][cc];
      v.z = tile[wd + 2][cc]; v.w = tile[wd + 3][cc];
      *reinterpret_cast<float4*>(out + ((size_t)b * E_ + e0 + cc) * P_ + p0 + wd) = v;
    }
  }
}

// ---------------------------------------------------------------------------
// Fallback (only if workspace is too small): naive but correct.
// ---------------------------------------------------------------------------
__global__ __launch_bounds__(256) void naive_kernel(
    const float* __restrict__ x, const float* __restrict__ W,
    const float* __restrict__ bias, float* __restrict__ out) {
  const size_t idx = (size_t)blockIdx.x * 256 + threadIdx.x;
  const int p = (int)(idx & 127);
  const int e = (int)((idx >> 7) & 127);
  const int b = (int)(idx >> 14);
  float acc = bias[p * E_ + e];
  const float* xp = x + (size_t)b * D_ * P_ + p;
  const float* wp = W + (size_t)p * D_ * E_ + e;
  for (int d = 0; d < D_; ++d) acc += xp[(size_t)d * P_] * wp[(size_t)d * E_];
  out[idx] = acc;
}

extern "C" void kernel_launch(void* const* d_in, const int* in_sizes, int n_in,
                              void* d_out, int out_size, void* d_ws, size_t ws_size,
                              hipStream_t stream) {
  (void)in_sizes; (void)n_in; (void)out_size;
  const float* x    = (const float*)d_in[0];   // [B,D,P] f32
  const float* W    = (const float*)d_in[1];   // [P,D,E] f32
  const float* bias = (const float*)d_in[2];   // [P,E]   f32
  float* out = (float*)d_out;                  // [B,E,P] f32

  const size_t xT_bytes  = (size_t)P_ * B_ * D_ * 2;   // 32 MiB
  const size_t Wt_bytes  = (size_t)P_ * E_ * D_ * 2;   // 16 MiB
  const size_t ws2_bytes = (size_t)P_ * B_ * E_ * 2;   // 8 MiB

  if (ws_size < xT_bytes + Wt_bytes + ws2_bytes) {
    naive_kernel<<<dim3((B_ * E_ * P_) / 256), 256, 0, stream>>>(x, W, bias, out);
    return;
  }

  u16* xT  = (u16*)d_ws;                                    // [P][B][64 kc][8]
  u16* Wt  = (u16*)((char*)d_ws + xT_bytes);                // [P][E][64 kc][8]
  u16* ws2 = (u16*)((char*)d_ws + xT_bytes + Wt_bytes);     // [P][B][E]

  // x: 1024 blocks (256 b x 4 d-blocks); W: 512 blocks (128 p x 4)
  prep_kernel<<<dim3(1536), 256, 0, stream>>>(x, W, xT, Wt);
  gemm_kernel<<<dim3(256), 512, 0, stream>>>(xT, Wt, bias, ws2);
  out_transpose_kernel<<<dim3(B_, 2, 2), 256, 0, stream>>>(ws2, out);
}